// Round 1
// baseline (373.224 us; speedup 1.0000x reference)
//
#include <hip/hip_runtime.h>

#define S_LEN 2048
#define EMB 2048
#define NH 16
#define KVH 4
#define DH 128

typedef __bf16 bf16x8 __attribute__((ext_vector_type(8)));
typedef float floatx4 __attribute__((ext_vector_type(4)));
typedef unsigned short ushortx8 __attribute__((ext_vector_type(8)));
typedef unsigned short ushortx4 __attribute__((ext_vector_type(4)));

static __device__ __forceinline__ unsigned short f2bf(float f) {
  unsigned u = __float_as_uint(f);
  return (unsigned short)((u + 0x7fffu + ((u >> 16) & 1u)) >> 16);
}

// async 16B global -> LDS (wave-uniform LDS base + lane*16)
static __device__ __forceinline__ void gload16(const unsigned short* g, unsigned short* l) {
  __builtin_amdgcn_global_load_lds(
      (const __attribute__((address_space(1))) unsigned int*)(const void*)g,
      (__attribute__((address_space(3))) unsigned int*)(void*)l, 16, 0, 0);
}

// ---- fused preprocessing: qkv fp32->bf16 (blocks 0..12287) + weight
// ---- transpose/scale/convert to [N][K] bf16 (blocks 12288..22527)
__global__ __launch_bounds__(256) void pre_kernel(
    const float* __restrict__ q, const float* __restrict__ k, const float* __restrict__ v,
    const float* __restrict__ Wq, const float* __restrict__ Wk,
    const float* __restrict__ Wv, const float* __restrict__ Wo,
    unsigned short* __restrict__ qo, unsigned short* __restrict__ ko,
    unsigned short* __restrict__ vo,
    unsigned short* __restrict__ Wqt, unsigned short* __restrict__ Wkt,
    unsigned short* __restrict__ Wvt, unsigned short* __restrict__ Wot,
    float scale) {
  __shared__ float t[32][33];
  int bx = blockIdx.x;
  if (bx < 12288) {
    const int sel = bx >> 12;
    const float* in = (sel == 0) ? q : (sel == 1) ? k : v;
    unsigned short* out = (sel == 0) ? qo : (sel == 1) ? ko : vo;
    size_t i = (((size_t)(bx & 4095)) * 256 + threadIdx.x) * 8;
    floatx4 a = *(const floatx4*)(in + i);
    floatx4 bvec = *(const floatx4*)(in + i + 4);
    ushortx8 o;
    #pragma unroll
    for (int c = 0; c < 4; ++c) { o[c] = f2bf(a[c]); o[4 + c] = f2bf(bvec[c]); }
    *(ushortx8*)(out + i) = o;
  } else {
    bx -= 12288;
    const float* W; unsigned short* Wt; int N, tile; float sc;
    if (bx < 4096)      { W = Wq; Wt = Wqt; N = 2048; tile = bx;        sc = scale; }
    else if (bx < 5120) { W = Wk; Wt = Wkt; N = 512;  tile = bx - 4096; sc = scale; }
    else if (bx < 6144) { W = Wv; Wt = Wvt; N = 512;  tile = bx - 5120; sc = 1.0f; }
    else                { W = Wo; Wt = Wot; N = 2048; tile = bx - 6144; sc = 1.0f; }
    const int ntiles = N >> 5;
    const int n0 = (tile % ntiles) * 32, k0 = (tile / ntiles) * 32;
    const int tx = threadIdx.x & 31, ty = threadIdx.x >> 5;
    #pragma unroll
    for (int r = 0; r < 4; ++r)
      t[ty + r * 8][tx] = W[(size_t)(k0 + ty + r * 8) * N + n0 + tx];
    __syncthreads();
    #pragma unroll
    for (int r = 0; r < 4; ++r)
      Wt[(size_t)(n0 + ty + r * 8) * 2048 + k0 + tx] = f2bf(t[tx][ty + r * 8] * sc);
  }
}

// ================= 256x256 / BK=64 / 8-wave / 8-phase GEMM core =================
// Schedule (per K-tile, 4 phases; 2 K-tiles per unrolled iter = 8 phases):
//  P1: ds_read op1 kk0 (8xb128) + op2 kk0 (4) | BAR | lgkm0 | 16 MFMA (kk0,j0-1) | BAR
//  P2: ds_read op2 kk1 (4)                    | BAR | lgkm0 | 16 MFMA (kk0,j2-3) | BAR
//  P3: ds_read op1 kk1 (8)                    | BAR | lgkm0 | 16 MFMA (kk1,j0-1) | BAR
//  P4: issue 8x global_load_lds for tile t+2  | BAR |         16 MFMA (kk1,j2-3)
//      | s_waitcnt vmcnt(8)  (t+1 landed, t+2 stays in flight) | BAR
// Staging in P4 is race-free: every phase drains its own ds_reads (lgkmcnt(0))
// before its end-barrier, so after the P3-end barrier ALL waves' reads of the
// current buffer are complete; t+2 has the same parity and overwrites it safely.
static __device__ __forceinline__ void gemm256_core(
    const unsigned short* __restrict__ Ab, const unsigned short* __restrict__ Bb,
    bool swap, unsigned short* As, unsigned short* Bs, floatx4 (&acc)[8][4]) {
  const int tid = threadIdx.x;
  const int lane = tid & 63, w = tid >> 6;
  const int lm = lane & 15, gq = lane >> 4;
  const int wm = w >> 2, wn = w & 3;
  const int lr = lane >> 3, lc = (lane & 7) ^ lr;

  auto stageH = [&](const unsigned short* gb, unsigned short* lt, int half, int kst) {
    #pragma unroll
    for (int qq = 0; qq < 2; ++qq) {
      const int rb = half * 128 + w * 16 + qq * 8;
      gload16(gb + (((size_t)(rb + lr)) << 11) + kst + (lc << 3), lt + rb * 64);
    }
  };

  // prologue: stage tile0 (buf0) then tile1 (buf1); wait tile0 (8 oldest of 16)
  stageH(Ab, As, 0, 0);            stageH(Ab, As, 1, 0);
  stageH(Bb, Bs, 0, 0);            stageH(Bb, Bs, 1, 0);
  stageH(Ab, As + 16384, 0, 64);   stageH(Ab, As + 16384, 1, 64);
  stageH(Bb, Bs + 16384, 0, 64);   stageH(Bb, Bs + 16384, 1, 64);
  asm volatile("s_waitcnt vmcnt(8)" ::: "memory");
  __builtin_amdgcn_s_barrier();

  const int r1 = (wm * 128 + lm) * 64;             // op1 row base (frag i: +i*1024)
  const int r2 = (wn * 64 + lm) * 64;              // op2 row base (frag j: +j*1024)
  const int c0 = ((0 + gq) ^ (lm & 7)) * 8;        // kk0 chunk (XOR-swizzled)
  const int c1 = ((4 + gq) ^ (lm & 7)) * 8;        // kk1 chunk

#define TILE_BODY(AsC, BsC, KST, DOSTG)                                                         \
  {                                                                                             \
    const unsigned short* l1 = swap ? (BsC) : (AsC);                                            \
    const unsigned short* l2 = swap ? (AsC) : (BsC);                                            \
    bf16x8 op1[8], o2a[4], o2b[4];                                                              \
    _Pragma("unroll") for (int i = 0; i < 8; ++i)                                               \
      op1[i] = *(const bf16x8*)&l1[r1 + i * 1024 + c0];                                         \
    _Pragma("unroll") for (int j = 0; j < 4; ++j)                                               \
      o2a[j] = *(const bf16x8*)&l2[r2 + j * 1024 + c0];                                         \
    __builtin_amdgcn_s_barrier();                                                               \
    asm volatile("s_waitcnt lgkmcnt(0)" ::: "memory");                                          \
    __builtin_amdgcn_s_setprio(1);                                                              \
    _Pragma("unroll") for (int i = 0; i < 8; ++i) {                                             \
      acc[i][0] = __builtin_amdgcn_mfma_f32_16x16x32_bf16(op1[i], o2a[0], acc[i][0], 0, 0, 0);  \
      acc[i][1] = __builtin_amdgcn_mfma_f32_16x16x32_bf16(op1[i], o2a[1], acc[i][1], 0, 0, 0);  \
    }                                                                                           \
    __builtin_amdgcn_s_setprio(0);                                                              \
    __builtin_amdgcn_s_barrier();                                                               \
    _Pragma("unroll") for (int j = 0; j < 4; ++j)                                               \
      o2b[j] = *(const bf16x8*)&l2[r2 + j * 1024 + c1];                                         \
    __builtin_amdgcn_s_barrier();                                                               \
    asm volatile("s_waitcnt lgkmcnt(0)" ::: "memory");                                          \
    __builtin_amdgcn_s_setprio(1);                                                              \
    _Pragma("unroll") for (int i = 0; i < 8; ++i) {                                             \
      acc[i][2] = __builtin_amdgcn_mfma_f32_16x16x32_bf16(op1[i], o2a[2], acc[i][2], 0, 0, 0);  \
      acc[i][3] = __builtin_amdgcn_mfma_f32_16x16x32_bf16(op1[i], o2a[3], acc[i][3], 0, 0, 0);  \
    }                                                                                           \
    __builtin_amdgcn_s_setprio(0);                                                              \
    __builtin_amdgcn_s_barrier();                                                               \
    _Pragma("unroll") for (int i = 0; i < 8; ++i)                                               \
      op1[i] = *(const bf16x8*)&l1[r1 + i * 1024 + c1];                                         \
    __builtin_amdgcn_s_barrier();                                                               \
    asm volatile("s_waitcnt lgkmcnt(0)" ::: "memory");                                          \
    __builtin_amdgcn_s_setprio(1);                                                              \
    _Pragma("unroll") for (int i = 0; i < 8; ++i) {                                             \
      acc[i][0] = __builtin_amdgcn_mfma_f32_16x16x32_bf16(op1[i], o2b[0], acc[i][0], 0, 0, 0);  \
      acc[i][1] = __builtin_amdgcn_mfma_f32_16x16x32_bf16(op1[i], o2b[1], acc[i][1], 0, 0, 0);  \
    }                                                                                           \
    __builtin_amdgcn_s_setprio(0);                                                              \
    __builtin_amdgcn_s_barrier();                                                               \
    if (DOSTG) {                                                                                \
      stageH(Ab, (AsC), 0, (KST)); stageH(Ab, (AsC), 1, (KST));                                 \
      stageH(Bb, (BsC), 0, (KST)); stageH(Bb, (BsC), 1, (KST));                                 \
    }                                                                                           \
    __builtin_amdgcn_s_barrier();                                                               \
    __builtin_amdgcn_s_setprio(1);                                                              \
    _Pragma("unroll") for (int i = 0; i < 8; ++i) {                                             \
      acc[i][2] = __builtin_amdgcn_mfma_f32_16x16x32_bf16(op1[i], o2b[2], acc[i][2], 0, 0, 0);  \
      acc[i][3] = __builtin_amdgcn_mfma_f32_16x16x32_bf16(op1[i], o2b[3], acc[i][3], 0, 0, 0);  \
    }                                                                                           \
    __builtin_amdgcn_s_setprio(0);                                                              \
    if (DOSTG) { asm volatile("s_waitcnt vmcnt(8)" ::: "memory"); }                             \
    else       { asm volatile("s_waitcnt vmcnt(0)" ::: "memory"); }                             \
    __builtin_amdgcn_s_barrier();                                                               \
  }

  #pragma unroll 1
  for (int t = 0; t < 30; t += 2) {
    TILE_BODY(As, Bs, (t + 2) * 64, 1);
    TILE_BODY(As + 16384, Bs + 16384, (t + 3) * 64, 1);
  }
  TILE_BODY(As, Bs, 0, 0);
  TILE_BODY(As + 16384, Bs + 16384, 0, 0);
#undef TILE_BODY
}

// ---- merged Q/K/V projection GEMM: 192 blocks of 256x256, K=2048 ----
// Q,K swapped (op1=W -> reg dim = d); V normal (op1=data -> reg dim = s).
__global__ __launch_bounds__(512, 2) void proj_kernel(
    const unsigned short* __restrict__ qb, const unsigned short* __restrict__ kb,
    const unsigned short* __restrict__ vb,
    const unsigned short* __restrict__ Wqt, const unsigned short* __restrict__ Wkt,
    const unsigned short* __restrict__ Wvt,
    unsigned short* __restrict__ Qh, unsigned short* __restrict__ Kh,
    unsigned short* __restrict__ Vt) {
  extern __shared__ unsigned short lds[];
  unsigned short* As = lds;            // 2 x 16384
  unsigned short* Bs = lds + 32768;    // 2 x 16384
  int bid = (int)blockIdx.x;
  bid = (bid & 7) * 24 + (bid >> 3);   // XCD swizzle (192 % 8 == 0 -> bijective)
  const unsigned short *Ab, *Bb;
  int task, bn, bt;
  if (bid < 128)      { task = 0; bn = bid >> 4;         bt = bid & 15;         Ab = qb; Bb = Wqt; }
  else if (bid < 160) { task = 1; bn = (bid - 128) >> 4; bt = (bid - 128) & 15; Ab = kb; Bb = Wkt; }
  else                { task = 2; bn = (bid - 160) >> 4; bt = (bid - 160) & 15; Ab = vb; Bb = Wvt; }
  Ab += ((size_t)bt) << 19;   // bt*256*2048
  Bb += ((size_t)bn) << 19;

  floatx4 acc[8][4] = {};
  gemm256_core(Ab, Bb, task != 2, As, Bs, acc);

  const int tid = threadIdx.x, lane = tid & 63, w = tid >> 6;
  const int lm = lane & 15, gq = lane >> 4;
  const int wm = w >> 2, wn = w & 3;
  if (task != 2) {           // Q/K: rows=d (weight n-dim), cols=t
    unsigned short* outp = (task == 0) ? Qh : Kh;
    const int nheads = (task == 0) ? NH : KVH;
    const int head = bn * 2 + wm;
    #pragma unroll
    for (int i = 0; i < 8; ++i) {
      const int d0 = i * 16 + gq * 4;
      #pragma unroll
      for (int j = 0; j < 4; ++j) {
        const int tg = bt * 256 + wn * 64 + j * 16 + lm;
        const int b_ = tg >> 11, s_ = tg & 2047;
        ushortx4 pk;
        #pragma unroll
        for (int r = 0; r < 4; ++r) pk[r] = f2bf(acc[i][j][r]);
        *(ushortx4*)&outp[((size_t)(b_ * nheads + head) * S_LEN + s_) * DH + d0] = pk;
      }
    }
  } else {                   // V: rows=s, cols=d -> Vt [B,KVH,D,S]
    #pragma unroll
    for (int i = 0; i < 8; ++i) {
      const int sgl = bt * 256 + wm * 128 + i * 16 + gq * 4;
      const int b_ = sgl >> 11, s_ = sgl & 2047;
      #pragma unroll
      for (int j = 0; j < 4; ++j) {
        const int dl = wn * 64 + j * 16;
        const int head = bn * 2 + (dl >> 7);
        const int dd = (dl & 127) + lm;
        ushortx4 pk;
        #pragma unroll
        for (int r = 0; r < 4; ++r) pk[r] = f2bf(acc[i][j][r]);
        *(ushortx4*)&Vt[((size_t)(b_ * KVH + head) * DH + dd) * S_LEN + s_] = pk;
      }
    }
  }
}

// ---- final GEMM: out[t][n] fp32 = Z[t][k] * Wot[n][k]^T, 128 blocks 256x256 ----
__global__ __launch_bounds__(512, 2) void out_kernel(const unsigned short* __restrict__ Z,
                                                     const unsigned short* __restrict__ Wot,
                                                     float* __restrict__ outp) {
  extern __shared__ unsigned short lds[];
  unsigned short* As = lds;
  unsigned short* Bs = lds + 32768;
  int bid = (int)blockIdx.x;
  bid = (bid & 7) * 16 + (bid >> 3);   // XCD swizzle (128 % 8 == 0)
  const int bn = bid >> 4, bt = bid & 15;

  floatx4 acc[8][4] = {};
  gemm256_core(Z + (((size_t)bt) << 19), Wot + (((size_t)bn) << 19), true, As, Bs, acc);

  const int tid = threadIdx.x, lane = tid & 63, w = tid >> 6;
  const int lm = lane & 15, gq = lane >> 4;
  const int wm = w >> 2, wn = w & 3;
  #pragma unroll
  for (int i = 0; i < 8; ++i) {
    const int n0 = bn * 256 + wm * 128 + i * 16 + gq * 4;
    #pragma unroll
    for (int j = 0; j < 4; ++j) {
      const int tg = bt * 256 + wn * 64 + j * 16 + lm;
      *(floatx4*)&outp[(size_t)tg * 2048 + n0] = acc[i][j];
    }
  }
}

// ---- flash-style causal attention: LDS-staged K/V + register prefetch,
// ---- uniform work (qt = 31-bx then bx), swapped PV -> ushortx4 Z stores.
__global__ __launch_bounds__(256) void attn_kernel(const unsigned short* __restrict__ Qh,
                                                   const unsigned short* __restrict__ Kh,
                                                   const unsigned short* __restrict__ Vt,
                                                   unsigned short* __restrict__ Z) {
  __shared__ unsigned short Ks[64][136];
  __shared__ unsigned short Vs[128][72];
  __shared__ unsigned short Ps[4][16][80];  // stride 80: conflict-free scalar writes
  const int tid = threadIdx.x;
  const int w = tid >> 6, lane = tid & 63;
  const int lm = lane & 15, gq = lane >> 4;
  const int h = blockIdx.y, b = blockIdx.z;
  const unsigned short* Kp = Kh + (size_t)(b * KVH + (h >> 2)) * S_LEN * DH;
  const unsigned short* Vp = Vt + (size_t)(b * KVH + (h >> 2)) * DH * S_LEN;

  const int krow = tid >> 2, kq4 = tid & 3;
  const int vd = tid >> 1, vhf = tid & 1;

  ushortx8 kreg[4], vreg[4];
  {
    const unsigned short* ks = Kp + (size_t)krow * DH + kq4 * 32;
    const unsigned short* vs = Vp + (size_t)vd * S_LEN + vhf * 32;
    #pragma unroll
    for (int i = 0; i < 4; ++i) { kreg[i] = *(const ushortx8*)(ks + i * 8); vreg[i] = *(const ushortx8*)(vs + i * 8); }
  }

  bf16x8 ones;
  #pragma unroll
  for (int c = 0; c < 8; ++c) ones[c] = (__bf16)1.0f;

  #pragma unroll 1
  for (int pass = 0; pass < 2; ++pass) {
    const int qt = pass ? (int)blockIdx.x : 31 - (int)blockIdx.x;
    const int Q0 = qt * 64;
    const unsigned short* Qp = Qh + ((size_t)(b * NH + h) * S_LEN + Q0) * DH;
    bf16x8 qfr[4];
    #pragma unroll
    for (int kk = 0; kk < 4; ++kk)
      qfr[kk] = *(const bf16x8*)(Qp + (size_t)(w * 16 + lm) * DH + kk * 32 + gq * 8);

    floatx4 acc_o[8] = {};
    floatx4 acc_l = {};

    for (int it = 0; it <= qt; ++it) {
      const int kv0 = it * 64;
      __syncthreads();  // previous iter's LDS reads complete
      #pragma unroll
      for (int i = 0; i < 4; ++i) *(ushortx8*)&Ks[krow][kq4 * 32 + i * 8] = kreg[i];
      #pragma unroll
      for (int i = 0; i < 4; ++i) *(ushortx8*)&Vs[vd][vhf * 32 + i * 8] = vreg[i];
      __syncthreads();
      if (!(pass == 1 && it == qt)) {  // prefetch next tile (or pass-1 tile 0)
        const int kvn = (it < qt) ? kv0 + 64 : 0;
        const unsigned short* ks = Kp + (size_t)(kvn + krow) * DH + kq4 * 32;
        const unsigned short* vs = Vp + (size_t)vd * S_LEN + kvn + vhf * 32;
        #pragma unroll
        for (int i = 0; i < 4; ++i) { kreg[i] = *(const ushortx8*)(ks + i * 8); vreg[i] = *(const ushortx8*)(vs + i * 8); }
      }
      // S = Q K^T (normal orientation: rows=q, cols=kv)
      floatx4 sa[4] = {};
      #pragma unroll
      for (int j = 0; j < 4; ++j)
        #pragma unroll
        for (int kk = 0; kk < 4; ++kk) {
          bf16x8 bk = *(const bf16x8*)&Ks[j * 16 + lm][kk * 32 + gq * 8];
          sa[j] = __builtin_amdgcn_mfma_f32_16x16x32_bf16(qfr[kk], bk, sa[j], 0, 0, 0);
        }
      // masked exp -> Ps (per-wave private; same-wave ordering only)
      const int rowb = Q0 + w * 16 + gq * 4;
      #pragma unroll
      for (int r = 0; r < 4; ++r) {
        const int qg = rowb + r;
        #pragma unroll
        for (int j = 0; j < 4; ++j) {
          const int kg = kv0 + j * 16 + lm;
          const float p = (kg <= qg) ? __expf(sa[j][r]) : 0.0f;
          Ps[w][gq * 4 + r][j * 16 + lm] = f2bf(p);
        }
      }
      // P V swapped: op1=V (rows=d), op2=P as B-layout (cols=s) -> regs along d
      bf16x8 ap0 = *(const bf16x8*)&Ps[w][lm][gq * 8];
      bf16x8 ap1 = *(const bf16x8*)&Ps[w][lm][32 + gq * 8];
      #pragma unroll
      for (int jd = 0; jd < 8; ++jd) {
        bf16x8 bv0 = *(const bf16x8*)&Vs[jd * 16 + lm][gq * 8];
        bf16x8 bv1 = *(const bf16x8*)&Vs[jd * 16 + lm][32 + gq * 8];
        acc_o[jd] = __builtin_amdgcn_mfma_f32_16x16x32_bf16(bv0, ap0, acc_o[jd], 0, 0, 0);
        acc_o[jd] = __builtin_amdgcn_mfma_f32_16x16x32_bf16(bv1, ap1, acc_o[jd], 0, 0, 0);
      }
      acc_l = __builtin_amdgcn_mfma_f32_16x16x32_bf16(ones, ap0, acc_l, 0, 0, 0);
      acc_l = __builtin_amdgcn_mfma_f32_16x16x32_bf16(ones, ap1, acc_l, 0, 0, 0);
    }

    const float inv = 1.0f / acc_l[0];  // all 4 regs equal (row-sum per col s=lm)
    const size_t t_ = (size_t)b * S_LEN + Q0 + w * 16 + lm;
    #pragma unroll
    for (int jd = 0; jd < 8; ++jd) {
      ushortx4 pk;
      #pragma unroll
      for (int r = 0; r < 4; ++r) pk[r] = f2bf(acc_o[jd][r] * inv);
      *(ushortx4*)&Z[t_ * (NH * DH) + h * DH + jd * 16 + gq * 4] = pk;
    }
  }
}

extern "C" void kernel_launch(void* const* d_in, const int* in_sizes, int n_in,
                              void* d_out, int out_size, void* d_ws, size_t ws_size,
                              hipStream_t stream) {
  (void)in_sizes; (void)n_in; (void)out_size; (void)ws_size;
  const float* q  = (const float*)d_in[0];
  const float* k  = (const float*)d_in[1];
  const float* v  = (const float*)d_in[2];
  const float* Wq = (const float*)d_in[3];
  const float* Wk = (const float*)d_in[4];
  const float* Wv = (const float*)d_in[5];
  const float* Wo = (const float*)d_in[6];

  unsigned short* Qh  = (unsigned short*)d_ws;
  unsigned short* Kh  = Qh + (size_t)2 * NH * S_LEN * DH;
  unsigned short* Vt  = Kh + (size_t)2 * KVH * S_LEN * DH;
  unsigned short* Z   = Vt + (size_t)2 * KVH * S_LEN * DH;
  unsigned short* vb  = Z + (size_t)4096 * 2048;
  unsigned short* Wqt = vb + (size_t)4096 * 2048;
  unsigned short* Wkt = Wqt + (size_t)2048 * 2048;
  unsigned short* Wvt = Wkt + (size_t)512 * 2048;
  unsigned short* Wot = Wvt + (size_t)512 * 2048;
  // qb/kb live in d_out (dead before out_kernel writes d_out)
  unsigned short* qb = (unsigned short*)d_out;
  unsigned short* kb = qb + (size_t)4096 * 2048;

  const float scale = 0.29730177875068026f;  // 128^(-1/4), folded into Wq/Wk

  static int s_attr_done = 0;
  if (!s_attr_done) {
    hipFuncSetAttribute(reinterpret_cast<const void*>(proj_kernel),
                        hipFuncAttributeMaxDynamicSharedMemorySize, 131072);
    hipFuncSetAttribute(reinterpret_cast<const void*>(out_kernel),
                        hipFuncAttributeMaxDynamicSharedMemorySize, 131072);
    s_attr_done = 1;
  }

  pre_kernel<<<22528, 256, 0, stream>>>(q, k, v, Wq, Wk, Wv, Wo,
                                        qb, kb, vb, Wqt, Wkt, Wvt, Wot, scale);
  proj_kernel<<<192, 512, 131072, stream>>>(qb, kb, vb, Wqt, Wkt, Wvt, Qh, Kh, Vt);
  attn_kernel<<<dim3(16, 16, 2), 256, 0, stream>>>(Qh, Kh, Vt, Z);
  out_kernel<<<128, 512, 131072, stream>>>(Z, Wot, (float*)d_out);
}

// Round 2
// 355.790 us; speedup vs baseline: 1.0490x; 1.0490x over previous
//
#include <hip/hip_runtime.h>

#define S_LEN 2048
#define EMB 2048
#define NH 16
#define KVH 4
#define DH 128

typedef __bf16 bf16x8 __attribute__((ext_vector_type(8)));
typedef float floatx4 __attribute__((ext_vector_type(4)));
typedef unsigned short ushortx8 __attribute__((ext_vector_type(8)));
typedef unsigned short ushortx4 __attribute__((ext_vector_type(4)));

static __device__ __forceinline__ unsigned short f2bf(float f) {
  unsigned u = __float_as_uint(f);
  return (unsigned short)((u + 0x7fffu + ((u >> 16) & 1u)) >> 16);
}

// async 16B global -> LDS (wave-uniform LDS base + lane*16)
static __device__ __forceinline__ void gload16(const unsigned short* g, unsigned short* l) {
  __builtin_amdgcn_global_load_lds(
      (const __attribute__((address_space(1))) unsigned int*)(const void*)g,
      (__attribute__((address_space(3))) unsigned int*)(void*)l, 16, 0, 0);
}

// ---- fused preprocessing: qkv fp32->bf16 (blocks 0..12287) + weight
// ---- transpose/scale/convert to [N][K] bf16 (blocks 12288..22527)
__global__ __launch_bounds__(256) void pre_kernel(
    const float* __restrict__ q, const float* __restrict__ k, const float* __restrict__ v,
    const float* __restrict__ Wq, const float* __restrict__ Wk,
    const float* __restrict__ Wv, const float* __restrict__ Wo,
    unsigned short* __restrict__ qo, unsigned short* __restrict__ ko,
    unsigned short* __restrict__ vo,
    unsigned short* __restrict__ Wqt, unsigned short* __restrict__ Wkt,
    unsigned short* __restrict__ Wvt, unsigned short* __restrict__ Wot,
    float scale) {
  __shared__ float t[32][33];
  int bx = blockIdx.x;
  if (bx < 12288) {
    const int sel = bx >> 12;
    const float* in = (sel == 0) ? q : (sel == 1) ? k : v;
    unsigned short* out = (sel == 0) ? qo : (sel == 1) ? ko : vo;
    size_t i = (((size_t)(bx & 4095)) * 256 + threadIdx.x) * 8;
    floatx4 a = *(const floatx4*)(in + i);
    floatx4 bvec = *(const floatx4*)(in + i + 4);
    ushortx8 o;
    #pragma unroll
    for (int c = 0; c < 4; ++c) { o[c] = f2bf(a[c]); o[4 + c] = f2bf(bvec[c]); }
    *(ushortx8*)(out + i) = o;
  } else {
    bx -= 12288;
    const float* W; unsigned short* Wt; int N, tile; float sc;
    if (bx < 4096)      { W = Wq; Wt = Wqt; N = 2048; tile = bx;        sc = scale; }
    else if (bx < 5120) { W = Wk; Wt = Wkt; N = 512;  tile = bx - 4096; sc = scale; }
    else if (bx < 6144) { W = Wv; Wt = Wvt; N = 512;  tile = bx - 5120; sc = 1.0f; }
    else                { W = Wo; Wt = Wot; N = 2048; tile = bx - 6144; sc = 1.0f; }
    const int ntiles = N >> 5;
    const int n0 = (tile % ntiles) * 32, k0 = (tile / ntiles) * 32;
    const int tx = threadIdx.x & 31, ty = threadIdx.x >> 5;
    #pragma unroll
    for (int r = 0; r < 4; ++r)
      t[ty + r * 8][tx] = W[(size_t)(k0 + ty + r * 8) * N + n0 + tx];
    __syncthreads();
    #pragma unroll
    for (int r = 0; r < 4; ++r)
      Wt[(size_t)(n0 + ty + r * 8) * 2048 + k0 + tx] = f2bf(t[tx][ty + r * 8] * sc);
  }
}

// ================= 256x256 / BK=64 / 8-wave / 8-phase GEMM core =================
// Spread-staging schedule (body t reads buf p=t&1, other buf q):
//  P1: ds_read op1 c0 (8) + o2a (4) | stage A(t+1)h1 -> q | BAR lgkm0 MFMA[o2a01] BAR
//  P2: ds_read o2b (4)              | stage B(t+1)h0 -> q | BAR lgkm0 MFMA[o2a23] BAR
//  P3: ds_read op1 c1 (8)           | stage B(t+1)h1 -> q | BAR lgkm0 MFMA[o2b01] BAR
//  P4: stage A(t+2)h0 -> p | BAR | MFMA[o2b23] | vmcnt(2) | BAR
// Safety: writes to q in P1-P3 target data last read in body t-1 (drained at each
// wave's t-1.P3 lgkm0, all waves past t-1's final barrier). Write to p in P4 is
// after the P3-end barrier (all waves' reads of p drained). vmcnt(2) at P4 drains
// all of S(t+1) (8 loads) keeping A(t+2)h0 (2) in flight -> counted, never 0.
static __device__ __forceinline__ void gemm256_core(
    const unsigned short* __restrict__ Ab, const unsigned short* __restrict__ Bb,
    bool swap, unsigned short* As, unsigned short* Bs, floatx4 (&acc)[8][4]) {
  const int tid = threadIdx.x;
  const int lane = tid & 63, w = tid >> 6;
  const int lm = lane & 15, gq = lane >> 4;
  const int wm = w >> 2, wn = w & 3;
  const int lr = lane >> 3, lc = (lane & 7) ^ lr;

  auto stageH = [&](const unsigned short* gb, unsigned short* lt, int half, int kst) {
    #pragma unroll
    for (int qq = 0; qq < 2; ++qq) {
      const int rb = half * 128 + w * 16 + qq * 8;
      gload16(gb + (((size_t)(rb + lr)) << 11) + kst + (lc << 3), lt + rb * 64);
    }
  };

  unsigned short* As2 = As + 16384;
  unsigned short* Bs2 = Bs + 16384;

  // prologue: tile0 (all 4 halves) -> buf0; A(1)h0 -> buf1
  stageH(Ab, As, 0, 0);  stageH(Ab, As, 1, 0);
  stageH(Bb, Bs, 0, 0);  stageH(Bb, Bs, 1, 0);
  stageH(Ab, As2, 0, 64);
  asm volatile("s_waitcnt vmcnt(2)" ::: "memory");
  __builtin_amdgcn_s_barrier();

  const int r1 = (wm * 128 + lm) * 64;             // op1 row base (frag i: +i*1024)
  const int r2 = (wn * 64 + lm) * 64;              // op2 row base (frag j: +j*1024)
  const int c0 = ((0 + gq) ^ (lm & 7)) * 8;        // kk0 chunk (XOR-swizzled)
  const int c1 = ((4 + gq) ^ (lm & 7)) * 8;        // kk1 chunk

#define TILE_BODY(CA, CB, OA, OB, KS1, KS2, STG1, STG4)                                         \
  {                                                                                             \
    const unsigned short* l1 = swap ? (CB) : (CA);                                              \
    const unsigned short* l2 = swap ? (CA) : (CB);                                              \
    bf16x8 op1[8], o2a[4], o2b[4];                                                              \
    _Pragma("unroll") for (int i = 0; i < 8; ++i)                                               \
      op1[i] = *(const bf16x8*)&l1[r1 + i * 1024 + c0];                                         \
    _Pragma("unroll") for (int j = 0; j < 4; ++j)                                               \
      o2a[j] = *(const bf16x8*)&l2[r2 + j * 1024 + c0];                                         \
    if (STG1) stageH(Ab, (OA), 1, (KS1));                                                       \
    __builtin_amdgcn_s_barrier();                                                               \
    asm volatile("s_waitcnt lgkmcnt(0)" ::: "memory");                                          \
    __builtin_amdgcn_s_setprio(1);                                                              \
    _Pragma("unroll") for (int i = 0; i < 8; ++i) {                                             \
      acc[i][0] = __builtin_amdgcn_mfma_f32_16x16x32_bf16(op1[i], o2a[0], acc[i][0], 0, 0, 0);  \
      acc[i][1] = __builtin_amdgcn_mfma_f32_16x16x32_bf16(op1[i], o2a[1], acc[i][1], 0, 0, 0);  \
    }                                                                                           \
    __builtin_amdgcn_s_setprio(0);                                                              \
    __builtin_amdgcn_s_barrier();                                                               \
    _Pragma("unroll") for (int j = 0; j < 4; ++j)                                               \
      o2b[j] = *(const bf16x8*)&l2[r2 + j * 1024 + c1];                                         \
    if (STG1) stageH(Bb, (OB), 0, (KS1));                                                       \
    __builtin_amdgcn_s_barrier();                                                               \
    asm volatile("s_waitcnt lgkmcnt(0)" ::: "memory");                                          \
    __builtin_amdgcn_s_setprio(1);                                                              \
    _Pragma("unroll") for (int i = 0; i < 8; ++i) {                                             \
      acc[i][2] = __builtin_amdgcn_mfma_f32_16x16x32_bf16(op1[i], o2a[2], acc[i][2], 0, 0, 0);  \
      acc[i][3] = __builtin_amdgcn_mfma_f32_16x16x32_bf16(op1[i], o2a[3], acc[i][3], 0, 0, 0);  \
    }                                                                                           \
    __builtin_amdgcn_s_setprio(0);                                                              \
    __builtin_amdgcn_s_barrier();                                                               \
    _Pragma("unroll") for (int i = 0; i < 8; ++i)                                               \
      op1[i] = *(const bf16x8*)&l1[r1 + i * 1024 + c1];                                         \
    if (STG1) stageH(Bb, (OB), 1, (KS1));                                                       \
    __builtin_amdgcn_s_barrier();                                                               \
    asm volatile("s_waitcnt lgkmcnt(0)" ::: "memory");                                          \
    __builtin_amdgcn_s_setprio(1);                                                              \
    _Pragma("unroll") for (int i = 0; i < 8; ++i) {                                             \
      acc[i][0] = __builtin_amdgcn_mfma_f32_16x16x32_bf16(op1[i], o2b[0], acc[i][0], 0, 0, 0);  \
      acc[i][1] = __builtin_amdgcn_mfma_f32_16x16x32_bf16(op1[i], o2b[1], acc[i][1], 0, 0, 0);  \
    }                                                                                           \
    __builtin_amdgcn_s_setprio(0);                                                              \
    __builtin_amdgcn_s_barrier();                                                               \
    if (STG4) stageH(Ab, (CA), 0, (KS2));                                                       \
    __builtin_amdgcn_s_barrier();                                                               \
    __builtin_amdgcn_s_setprio(1);                                                              \
    _Pragma("unroll") for (int i = 0; i < 8; ++i) {                                             \
      acc[i][2] = __builtin_amdgcn_mfma_f32_16x16x32_bf16(op1[i], o2b[2], acc[i][2], 0, 0, 0);  \
      acc[i][3] = __builtin_amdgcn_mfma_f32_16x16x32_bf16(op1[i], o2b[3], acc[i][3], 0, 0, 0);  \
    }                                                                                           \
    __builtin_amdgcn_s_setprio(0);                                                              \
    if (STG4) { asm volatile("s_waitcnt vmcnt(2)" ::: "memory"); }                              \
    else      { asm volatile("s_waitcnt vmcnt(0)" ::: "memory"); }                              \
    __builtin_amdgcn_s_barrier();                                                               \
  }

  #pragma unroll 1
  for (int t = 0; t < 30; t += 2) {
    TILE_BODY(As, Bs, As2, Bs2, (t + 1) * 64, (t + 2) * 64, 1, 1);
    TILE_BODY(As2, Bs2, As, Bs, (t + 2) * 64, (t + 3) * 64, 1, 1);
  }
  TILE_BODY(As, Bs, As2, Bs2, 31 * 64, 0, 1, 0);
  TILE_BODY(As2, Bs2, As, Bs, 0, 0, 0, 0);
#undef TILE_BODY
}

// ---- merged Q/K/V projection GEMM: 192 blocks of 256x256, K=2048 ----
// Q,K swapped (op1=W -> reg dim = d); V normal (op1=data -> reg dim = s).
__global__ __launch_bounds__(512, 2) void proj_kernel(
    const unsigned short* __restrict__ qb, const unsigned short* __restrict__ kb,
    const unsigned short* __restrict__ vb,
    const unsigned short* __restrict__ Wqt, const unsigned short* __restrict__ Wkt,
    const unsigned short* __restrict__ Wvt,
    unsigned short* __restrict__ Qh, unsigned short* __restrict__ Kh,
    unsigned short* __restrict__ Vt) {
  extern __shared__ unsigned short lds[];
  unsigned short* As = lds;            // 2 x 16384
  unsigned short* Bs = lds + 32768;    // 2 x 16384
  int bid = (int)blockIdx.x;
  bid = (bid & 7) * 24 + (bid >> 3);   // XCD swizzle (192 % 8 == 0 -> bijective)
  const unsigned short *Ab, *Bb;
  int task, bn, bt;
  if (bid < 128)      { task = 0; bn = bid >> 4;         bt = bid & 15;         Ab = qb; Bb = Wqt; }
  else if (bid < 160) { task = 1; bn = (bid - 128) >> 4; bt = (bid - 128) & 15; Ab = kb; Bb = Wkt; }
  else                { task = 2; bn = (bid - 160) >> 4; bt = (bid - 160) & 15; Ab = vb; Bb = Wvt; }
  Ab += ((size_t)bt) << 19;   // bt*256*2048
  Bb += ((size_t)bn) << 19;

  floatx4 acc[8][4] = {};
  gemm256_core(Ab, Bb, task != 2, As, Bs, acc);

  const int tid = threadIdx.x, lane = tid & 63, w = tid >> 6;
  const int lm = lane & 15, gq = lane >> 4;
  const int wm = w >> 2, wn = w & 3;
  if (task != 2) {           // Q/K: rows=d (weight n-dim), cols=t
    unsigned short* outp = (task == 0) ? Qh : Kh;
    const int nheads = (task == 0) ? NH : KVH;
    const int head = bn * 2 + wm;
    #pragma unroll
    for (int i = 0; i < 8; ++i) {
      const int d0 = i * 16 + gq * 4;
      #pragma unroll
      for (int j = 0; j < 4; ++j) {
        const int tg = bt * 256 + wn * 64 + j * 16 + lm;
        const int b_ = tg >> 11, s_ = tg & 2047;
        ushortx4 pk;
        #pragma unroll
        for (int r = 0; r < 4; ++r) pk[r] = f2bf(acc[i][j][r]);
        *(ushortx4*)&outp[((size_t)(b_ * nheads + head) * S_LEN + s_) * DH + d0] = pk;
      }
    }
  } else {                   // V: rows=s, cols=d -> Vt [B,KVH,D,S]
    #pragma unroll
    for (int i = 0; i < 8; ++i) {
      const int sgl = bt * 256 + wm * 128 + i * 16 + gq * 4;
      const int b_ = sgl >> 11, s_ = sgl & 2047;
      #pragma unroll
      for (int j = 0; j < 4; ++j) {
        const int dl = wn * 64 + j * 16;
        const int head = bn * 2 + (dl >> 7);
        const int dd = (dl & 127) + lm;
        ushortx4 pk;
        #pragma unroll
        for (int r = 0; r < 4; ++r) pk[r] = f2bf(acc[i][j][r]);
        *(ushortx4*)&Vt[((size_t)(b_ * KVH + head) * DH + dd) * S_LEN + s_] = pk;
      }
    }
  }
}

// ---- final GEMM: out[t][n] fp32 = Z[t][k] * Wot[n][k]^T, 128 blocks 256x256 ----
__global__ __launch_bounds__(512, 2) void out_kernel(const unsigned short* __restrict__ Z,
                                                     const unsigned short* __restrict__ Wot,
                                                     float* __restrict__ outp) {
  extern __shared__ unsigned short lds[];
  unsigned short* As = lds;
  unsigned short* Bs = lds + 32768;
  int bid = (int)blockIdx.x;
  bid = (bid & 7) * 16 + (bid >> 3);   // XCD swizzle (128 % 8 == 0)
  const int bn = bid >> 4, bt = bid & 15;

  floatx4 acc[8][4] = {};
  gemm256_core(Z + (((size_t)bt) << 19), Wot + (((size_t)bn) << 19), true, As, Bs, acc);

  const int tid = threadIdx.x, lane = tid & 63, w = tid >> 6;
  const int lm = lane & 15, gq = lane >> 4;
  const int wm = w >> 2, wn = w & 3;
  #pragma unroll
  for (int i = 0; i < 8; ++i) {
    const int n0 = bn * 256 + wm * 128 + i * 16 + gq * 4;
    #pragma unroll
    for (int j = 0; j < 4; ++j) {
      const int tg = bt * 256 + wn * 64 + j * 16 + lm;
      *(floatx4*)&outp[(size_t)tg * 2048 + n0] = acc[i][j];
    }
  }
}

// ---- flash-style causal attention: LDS-staged K/V + register prefetch,
// ---- uniform work (qt = 31-bx then bx), swapped PV -> ushortx4 Z stores.
__global__ __launch_bounds__(256) void attn_kernel(const unsigned short* __restrict__ Qh,
                                                   const unsigned short* __restrict__ Kh,
                                                   const unsigned short* __restrict__ Vt,
                                                   unsigned short* __restrict__ Z) {
  __shared__ unsigned short Ks[64][136];
  __shared__ unsigned short Vs[128][72];
  // stride 88: 44 dwords == 12 (mod 32) -> u16 stores spread 16 banks (~2-way),
  // b128 reads stay at the wave64 minimum. (stride 80 == 8 mod 32 put all 64
  // lanes' stores on 8 banks -> the 1.3e7 SQ_LDS_BANK_CONFLICT.)
  __shared__ unsigned short Ps[4][16][88];
  const int tid = threadIdx.x;
  const int w = tid >> 6, lane = tid & 63;
  const int lm = lane & 15, gq = lane >> 4;
  const int h = blockIdx.y, b = blockIdx.z;
  const unsigned short* Kp = Kh + (size_t)(b * KVH + (h >> 2)) * S_LEN * DH;
  const unsigned short* Vp = Vt + (size_t)(b * KVH + (h >> 2)) * DH * S_LEN;

  const int krow = tid >> 2, kq4 = tid & 3;
  const int vd = tid >> 1, vhf = tid & 1;

  ushortx8 kreg[4], vreg[4];
  {
    const unsigned short* ks = Kp + (size_t)krow * DH + kq4 * 32;
    const unsigned short* vs = Vp + (size_t)vd * S_LEN + vhf * 32;
    #pragma unroll
    for (int i = 0; i < 4; ++i) { kreg[i] = *(const ushortx8*)(ks + i * 8); vreg[i] = *(const ushortx8*)(vs + i * 8); }
  }

  bf16x8 ones;
  #pragma unroll
  for (int c = 0; c < 8; ++c) ones[c] = (__bf16)1.0f;

  #pragma unroll 1
  for (int pass = 0; pass < 2; ++pass) {
    const int qt = pass ? (int)blockIdx.x : 31 - (int)blockIdx.x;
    const int Q0 = qt * 64;
    const unsigned short* Qp = Qh + ((size_t)(b * NH + h) * S_LEN + Q0) * DH;
    bf16x8 qfr[4];
    #pragma unroll
    for (int kk = 0; kk < 4; ++kk)
      qfr[kk] = *(const bf16x8*)(Qp + (size_t)(w * 16 + lm) * DH + kk * 32 + gq * 8);

    floatx4 acc_o[8] = {};
    floatx4 acc_l = {};

    for (int it = 0; it <= qt; ++it) {
      const int kv0 = it * 64;
      __syncthreads();  // previous iter's LDS reads complete
      #pragma unroll
      for (int i = 0; i < 4; ++i) *(ushortx8*)&Ks[krow][kq4 * 32 + i * 8] = kreg[i];
      #pragma unroll
      for (int i = 0; i < 4; ++i) *(ushortx8*)&Vs[vd][vhf * 32 + i * 8] = vreg[i];
      __syncthreads();
      if (!(pass == 1 && it == qt)) {  // prefetch next tile (or pass-1 tile 0)
        const int kvn = (it < qt) ? kv0 + 64 : 0;
        const unsigned short* ks = Kp + (size_t)(kvn + krow) * DH + kq4 * 32;
        const unsigned short* vs = Vp + (size_t)vd * S_LEN + kvn + vhf * 32;
        #pragma unroll
        for (int i = 0; i < 4; ++i) { kreg[i] = *(const ushortx8*)(ks + i * 8); vreg[i] = *(const ushortx8*)(vs + i * 8); }
      }
      // S = Q K^T (normal orientation: rows=q, cols=kv)
      floatx4 sa[4] = {};
      #pragma unroll
      for (int j = 0; j < 4; ++j)
        #pragma unroll
        for (int kk = 0; kk < 4; ++kk) {
          bf16x8 bk = *(const bf16x8*)&Ks[j * 16 + lm][kk * 32 + gq * 8];
          sa[j] = __builtin_amdgcn_mfma_f32_16x16x32_bf16(qfr[kk], bk, sa[j], 0, 0, 0);
        }
      // masked exp -> Ps (per-wave private; same-wave ordering only)
      const int rowb = Q0 + w * 16 + gq * 4;
      #pragma unroll
      for (int r = 0; r < 4; ++r) {
        const int qg = rowb + r;
        #pragma unroll
        for (int j = 0; j < 4; ++j) {
          const int kg = kv0 + j * 16 + lm;
          const float p = (kg <= qg) ? __expf(sa[j][r]) : 0.0f;
          Ps[w][gq * 4 + r][j * 16 + lm] = __builtin_bit_cast(unsigned short, (__bf16)p);
        }
      }
      // P V swapped: op1=V (rows=d), op2=P as B-layout (cols=s) -> regs along d
      bf16x8 ap0 = *(const bf16x8*)&Ps[w][lm][gq * 8];
      bf16x8 ap1 = *(const bf16x8*)&Ps[w][lm][32 + gq * 8];
      #pragma unroll
      for (int jd = 0; jd < 8; ++jd) {
        bf16x8 bv0 = *(const bf16x8*)&Vs[jd * 16 + lm][gq * 8];
        bf16x8 bv1 = *(const bf16x8*)&Vs[jd * 16 + lm][32 + gq * 8];
        acc_o[jd] = __builtin_amdgcn_mfma_f32_16x16x32_bf16(bv0, ap0, acc_o[jd], 0, 0, 0);
        acc_o[jd] = __builtin_amdgcn_mfma_f32_16x16x32_bf16(bv1, ap1, acc_o[jd], 0, 0, 0);
      }
      acc_l = __builtin_amdgcn_mfma_f32_16x16x32_bf16(ones, ap0, acc_l, 0, 0, 0);
      acc_l = __builtin_amdgcn_mfma_f32_16x16x32_bf16(ones, ap1, acc_l, 0, 0, 0);
    }

    const float inv = 1.0f / acc_l[0];  // all 4 regs equal (row-sum per col s=lm)
    const size_t t_ = (size_t)b * S_LEN + Q0 + w * 16 + lm;
    #pragma unroll
    for (int jd = 0; jd < 8; ++jd) {
      ushortx4 pk;
      #pragma unroll
      for (int r = 0; r < 4; ++r) pk[r] = f2bf(acc_o[jd][r] * inv);
      *(ushortx4*)&Z[t_ * (NH * DH) + h * DH + jd * 16 + gq * 4] = pk;
    }
  }
}

extern "C" void kernel_launch(void* const* d_in, const int* in_sizes, int n_in,
                              void* d_out, int out_size, void* d_ws, size_t ws_size,
                              hipStream_t stream) {
  (void)in_sizes; (void)n_in; (void)out_size; (void)ws_size;
  const float* q  = (const float*)d_in[0];
  const float* k  = (const float*)d_in[1];
  const float* v  = (const float*)d_in[2];
  const float* Wq = (const float*)d_in[3];
  const float* Wk = (const float*)d_in[4];
  const float* Wv = (const float*)d_in[5];
  const float* Wo = (const float*)d_in[6];

  unsigned short* Qh  = (unsigned short*)d_ws;
  unsigned short* Kh  = Qh + (size_t)2 * NH * S_LEN * DH;
  unsigned short* Vt  = Kh + (size_t)2 * KVH * S_LEN * DH;
  unsigned short* Z   = Vt + (size_t)2 * KVH * S_LEN * DH;
  unsigned short* vb  = Z + (size_t)4096 * 2048;
  unsigned short* Wqt = vb + (size_t)4096 * 2048;
  unsigned short* Wkt = Wqt + (size_t)2048 * 2048;
  unsigned short* Wvt = Wkt + (size_t)512 * 2048;
  unsigned short* Wot = Wvt + (size_t)512 * 2048;
  // qb/kb live in d_out (dead before out_kernel writes d_out)
  unsigned short* qb = (unsigned short*)d_out;
  unsigned short* kb = qb + (size_t)4096 * 2048;

  const float scale = 0.29730177875068026f;  // 128^(-1/4), folded into Wq/Wk

  static int s_attr_done = 0;
  if (!s_attr_done) {
    hipFuncSetAttribute(reinterpret_cast<const void*>(proj_kernel),
                        hipFuncAttributeMaxDynamicSharedMemorySize, 131072);
    hipFuncSetAttribute(reinterpret_cast<const void*>(out_kernel),
                        hipFuncAttributeMaxDynamicSharedMemorySize, 131072);
    s_attr_done = 1;
  }

  pre_kernel<<<22528, 256, 0, stream>>>(q, k, v, Wq, Wk, Wv, Wo,
                                        qb, kb, vb, Wqt, Wkt, Wvt, Wot, scale);
  proj_kernel<<<192, 512, 131072, stream>>>(qb, kb, vb, Wqt, Wkt, Wvt, Qh, Kh, Vt);
  attn_kernel<<<dim3(16, 16, 2), 256, 0, stream>>>(Qh, Kh, Vt, Z);
  out_kernel<<<128, 512, 131072, stream>>>(Z, Wot, (float*)d_out);
}